// Round 1
// 253.349 us; speedup vs baseline: 1.0491x; 1.0491x over previous
//
#include <hip/hip_runtime.h>
#include <stdint.h>

// LinearAttend: q,k,v (4,8,64,8192) fp32.
//   out[j][s] = sum_i (C'[i][j]/rowsum[i]) * 0.125 * exp(q[i][s])/colsum[s]
//   C'[i][j]  = sum_s exp(k[i][s]) * v[j][s]
// Split-bf16 MFMA (x = hi + lo, 3 MFMAs), error ~2^-18 relative.
//
// ctx v2: wave-owns-tiles. 8 waves/block; wave w owns output tiles
// (mt=w>>1, nt=(w&1)*2 +{0,1}) over the whole 512-col chunk -> acc is 8 regs
// (was 64), no cross-wave merge. K/V staged to LDS via global_load_lds
// (contiguous 256B row segments), double-buffered, counted vmcnt(4) so next
// tile's loads fly under current tile's compute. XOR source-swizzle so
// ds_read_b128 of 16 rows x 32B is 2-way (free) instead of 16-way conflict.

typedef __attribute__((ext_vector_type(8))) short bf16x8;
typedef __attribute__((ext_vector_type(4))) float floatx4;

constexpr int D = 64, S = 8192, HEADS = 32;
constexpr int NC = 16;               // ctx chunks per head
constexpr int CHUNK = S / NC;        // 512 s per ctx block
constexpr int NT = CHUNK / 64;       // 8 col-tiles of 64 per block

__device__ __forceinline__ short bf16_rn(float x) {
    unsigned u = __builtin_bit_cast(unsigned, x);
    return (short)((u + 0x8000u) >> 16);
}
__device__ __forceinline__ float bf16_f(short h) {
    unsigned u = ((unsigned)(unsigned short)h) << 16;
    return __builtin_bit_cast(float, u);
}
__device__ __forceinline__ void split8(const float* x, bf16x8& hi, bf16x8& lo) {
#pragma unroll
    for (int e = 0; e < 8; ++e) {
        short h = bf16_rn(x[e]);
        hi[e] = h;
        lo[e] = bf16_rn(x[e] - bf16_f(h));
    }
}

__device__ __forceinline__ void gl16(const void* g, void* l) {
    __builtin_amdgcn_global_load_lds(
        (const __attribute__((address_space(1))) unsigned int*)g,
        (__attribute__((address_space(3))) unsigned int*)l, 16, 0, 0);
}

// ---------------------------------------------------------------- ctx ----
// Grid (32 heads, 16 chunks) x 512. LDS: 2 bufs x (K[64][64] + V[64][64]) fp32
// = 64 KiB -> 2 blocks/CU. LDS slot (r,t) holds data[r][t ^ (r&7)] (16B units):
// staged linearly by global_load_lds from an inverse-swizzled source address,
// read back with the same XOR.
__global__ __launch_bounds__(512, 4) void ctx_kernel(
    const float* __restrict__ K, const float* __restrict__ V,
    float* __restrict__ Cpart,   // [h][c][tile][reg][lane]
    float* __restrict__ Rpart)   // [h][c][64] rowsums
{
    __shared__ char smem[2 * 2 * 16384];
    const int h = blockIdx.x, c = blockIdx.y;
    const int wave = threadIdx.x >> 6, lane = threadIdx.x & 63;
    const int m = lane & 15, quad = lane >> 4;

    const float* Kb = K + (size_t)h * D * S;
    const float* Vb = V + (size_t)h * D * S;
    const int c0 = c * CHUNK;

    // staging: 32 gload_lds instrs/tile (16 K-rows*4 + 16 V-rows*4), 4/wave
    const int ii = wave << 2;              // first of my 4 stage instrs
    const int smat = ii >> 4;              // 0 -> K rows, 1 -> V rows
    const int r0base = (ii & 15) << 2;
    const float* gmat = smat ? Vb : Kb;

    auto stage = [&](int buf, int t) {
        const int colf = c0 + (t << 6);
#pragma unroll
        for (int g = 0; g < 4; ++g) {
            const int r0 = r0base + (g << 2);         // wave-uniform
            const int r = r0 + (lane >> 4);
            const int su = (lane & 15) ^ (r & 7);     // inverse source swizzle
            const float* src = gmat + (size_t)r * S + colf + (su << 2);
            char* dst = smem + (buf << 15) + (smat << 14) + (r0 << 8);
            gl16(src, dst);                           // lane writes dst+lane*16
        }
    };

    const int mt = wave >> 1, nt0 = (wave & 1) << 1;
    const int rA = mt * 16 + m;
    floatx4 acc[2];
    acc[0] = (floatx4){0.f, 0.f, 0.f, 0.f};
    acc[1] = (floatx4){0.f, 0.f, 0.f, 0.f};
    float rs = 0.f;

    stage(0, 0);
    for (int t = 0; t < NT; ++t) {
        if (t + 1 < NT) {
            stage((t + 1) & 1, t + 1);                    // prefetch next tile
            asm volatile("s_waitcnt vmcnt(4)" ::: "memory");  // my cur loads done
        } else {
            asm volatile("s_waitcnt vmcnt(0)" ::: "memory");
        }
        asm volatile("s_barrier" ::: "memory");           // all waves' cur done

        const char* kb = smem + ((t & 1) << 15);
        const char* vb = kb + 16384;
#pragma unroll
        for (int ks = 0; ks < 2; ++ks) {
            const int u0 = (ks << 3) + (quad << 1);
            float ar[8];
            const char* kr = kb + (rA << 8);
            *(float4*)&ar[0] = *(const float4*)(kr + ((u0 ^ (rA & 7)) << 4));
            *(float4*)&ar[4] = *(const float4*)(kr + (((u0 + 1) ^ (rA & 7)) << 4));
            float ex[8];
#pragma unroll
            for (int e = 0; e < 8; ++e) {
                ex[e] = __expf(ar[e]);
                rs += ex[e];
            }
            bf16x8 ah, al;
            split8(ex, ah, al);
#pragma unroll
            for (int j = 0; j < 2; ++j) {
                const int rB = (nt0 + j) * 16 + m;
                float br[8];
                const char* vr = vb + (rB << 8);
                *(float4*)&br[0] = *(const float4*)(vr + ((u0 ^ (rB & 7)) << 4));
                *(float4*)&br[4] = *(const float4*)(vr + (((u0 + 1) ^ (rB & 7)) << 4));
                bf16x8 bh, bl;
                split8(br, bh, bl);
                acc[j] = __builtin_amdgcn_mfma_f32_16x16x32_bf16(ah, bh, acc[j], 0, 0, 0);
                acc[j] = __builtin_amdgcn_mfma_f32_16x16x32_bf16(ah, bl, acc[j], 0, 0, 0);
                acc[j] = __builtin_amdgcn_mfma_f32_16x16x32_bf16(al, bh, acc[j], 0, 0, 0);
            }
        }
        asm volatile("s_barrier" ::: "memory");  // reads done before next overwrite
    }

    // rowsum: butterfly over quad bits -> totals at all lanes
    rs += __shfl_xor(rs, 16, 64);
    rs += __shfl_xor(rs, 32, 64);

    const size_t pbase = (((size_t)h * NC + c) << 12);
#pragma unroll
    for (int j = 0; j < 2; ++j)
#pragma unroll
        for (int r = 0; r < 4; ++r)
            Cpart[pbase + ((size_t)(((mt * 4 + nt0 + j) * 4 + r)) << 6) + lane] =
                acc[j][r];
    if ((wave & 1) == 0 && lane < 16)
        Rpart[(((size_t)h * NC + c) << 6) + mt * 16 + lane] = rs;
}

// ------------------------------------------------------------- reduce ----
// Grid (32 heads, 8 parts) x 256: 256 blocks (was 32 -> latency-bound).
// Element (tile,reg,lane): i = mt*16 + (lane>>4)*4 + reg, j = nt*16 + (lane&15).
// Write CnT[j][i] = sum * 0.125 / rowsum[i].
__global__ __launch_bounds__(256) void reduce_kernel(
    const float* __restrict__ Cpart, const float* __restrict__ Rpart,
    float* __restrict__ CnT)
{
    __shared__ float invr[D];
    const int h = blockIdx.x, p = blockIdx.y, t = threadIdx.x;

    if (t < D) {
        float s = 0.f;
#pragma unroll
        for (int c = 0; c < NC; ++c)
            s += Rpart[(((size_t)h * NC + c) << 6) + t];
        invr[t] = 0.125f / s;
    }
    __syncthreads();

#pragma unroll
    for (int k = 0; k < 2; ++k) {
        const int idx = (p << 9) + (k << 8) + t;
        float s = 0.f;
#pragma unroll
        for (int c = 0; c < NC; ++c)
            s += Cpart[(((size_t)h * NC + c) << 12) + idx];
        const int tile = idx >> 8, reg = (idx >> 6) & 3, lane = idx & 63;
        const int mtl = tile >> 2, ntl = tile & 3;
        const int i = mtl * 16 + ((lane >> 4) << 2) + reg;
        const int j = ntl * 16 + (lane & 15);
        CnT[((size_t)h << 12) + j * 64 + i] = s * invr[i];
    }
}

// ---------------------------------------------------------------- out ----
// Grid (32 heads, 16) x 256. Wave covers 128 s (8 iters of 16 s).
// A = CnT rows (preloaded/split once), B = exp(q) columns; colsum via
// quad butterfly; divide at epilogue. No LDS. (Unchanged this round.)
__global__ __launch_bounds__(256) void out_kernel(
    const float* __restrict__ Q, const float* __restrict__ CnT,
    float* __restrict__ Out)
{
    const int h = blockIdx.x;
    const int wave = threadIdx.x >> 6, lane = threadIdx.x & 63;
    const int m = lane & 15, quad = lane >> 4;
    const int sbase = (blockIdx.y * 4 + wave) * 128;

    bf16x8 Ah[4][2], Al[4][2];
    const float* Cb = CnT + (size_t)h * 4096;
#pragma unroll
    for (int jt = 0; jt < 4; ++jt)
#pragma unroll
        for (int kk = 0; kk < 2; ++kk) {
            float a[8];
            const float* p = Cb + (jt * 16 + m) * 64 + kk * 32 + quad * 8;
            *(float4*)&a[0] = *(const float4*)p;
            *(float4*)&a[4] = *(const float4*)(p + 4);
            split8(a, Ah[jt][kk], Al[jt][kk]);
        }

    const float* Qb = Q + (size_t)h * D * S;
    float* Ob = Out + (size_t)h * D * S;

    for (int it = 0; it < 8; ++it) {
        const int scol = sbase + it * 16 + m;
        float e[16];
        float cs = 0.f;
#pragma unroll
        for (int kk = 0; kk < 2; ++kk)
#pragma unroll
            for (int j2 = 0; j2 < 8; ++j2) {
                const float qv = Qb[(size_t)(kk * 32 + quad * 8 + j2) * S + scol];
                const float ev = __expf(qv);
                e[kk * 8 + j2] = ev;
                cs += ev;
            }
        cs += __shfl_xor(cs, 16, 64);
        cs += __shfl_xor(cs, 32, 64);
        const float inv = 1.0f / cs;

        bf16x8 Bh[2], Bl[2];
        split8(&e[0], Bh[0], Bl[0]);
        split8(&e[8], Bh[1], Bl[1]);

#pragma unroll
        for (int jt = 0; jt < 4; ++jt) {
            floatx4 a = (floatx4){0.f, 0.f, 0.f, 0.f};
#pragma unroll
            for (int kk = 0; kk < 2; ++kk) {
                a = __builtin_amdgcn_mfma_f32_16x16x32_bf16(Ah[jt][kk], Bh[kk], a, 0, 0, 0);
                a = __builtin_amdgcn_mfma_f32_16x16x32_bf16(Ah[jt][kk], Bl[kk], a, 0, 0, 0);
                a = __builtin_amdgcn_mfma_f32_16x16x32_bf16(Al[jt][kk], Bh[kk], a, 0, 0, 0);
            }
#pragma unroll
            for (int r = 0; r < 4; ++r)
                Ob[(size_t)(jt * 16 + quad * 4 + r) * S + scol] = a[r] * inv;
        }
    }
}

extern "C" void kernel_launch(void* const* d_in, const int* in_sizes, int n_in,
                              void* d_out, int out_size, void* d_ws, size_t ws_size,
                              hipStream_t stream) {
    const float* q = (const float*)d_in[0];
    const float* k = (const float*)d_in[1];
    const float* v = (const float*)d_in[2];
    float* out = (float*)d_out;

    float* Cpart = (float*)d_ws;                           // 32*16*4096*4 = 8.39 MB
    float* Rpart = Cpart + (size_t)HEADS * NC * 4096;      // 128 KB
    float* CnT   = Rpart + (size_t)HEADS * NC * 64;        // 512 KB

    ctx_kernel<<<dim3(HEADS, NC), 512, 0, stream>>>(k, v, Cpart, Rpart);
    reduce_kernel<<<dim3(HEADS, 8), 256, 0, stream>>>(Cpart, Rpart, CnT);
    out_kernel<<<dim3(HEADS, 16), 256, 0, stream>>>(q, CnT, out);
}